// Round 1
// baseline (16.515 us; speedup 1.0000x reference)
//
#include <hip/hip_runtime.h>

// PointGraphic2d: 4096x4096 f32 canvas, zero everywhere except a ~40px-wide
// disk around p = key_points[0] * 4096. Memory-bound: 64 MiB write.
// Strategy: single fused kernel, float4 stores, grid-stride; per-chunk cheap
// rejection tests so ~all threads just store zeros.

__global__ __launch_bounds__(256) void point_graphic2d_kernel(
    const float* __restrict__ key_points, float* __restrict__ out) {
  constexpr int H = 4096;
  constexpr int W = 4096;
  constexpr float WIDTH = 20.0f;
  constexpr float EPS = 0.001f;
  // max_distance = sqrt(4096^2 + 4096^2) = 4096*sqrt(2)
  constexpr float INV_MAXD = 1.0f / 5792.61880957152f;

  // point in pixel coords (same for all threads; L1-cached scalar-ish load)
  const float py = key_points[0] * (float)H;
  const float px = key_points[1] * (float)W;

  constexpr int N4 = (H * W) / 4;  // float4 chunks per canvas: 4,194,304
  const int stride = gridDim.x * blockDim.x;

  for (int i = blockIdx.x * blockDim.x + threadIdx.x; i < N4; i += stride) {
    const int y  = i >> 10;          // 1024 float4 chunks per row
    const int x0 = (i & 1023) << 2;  // first pixel x of this chunk

    float vv[4] = {0.0f, 0.0f, 0.0f, 0.0f};

    const float dy = (float)y - py;
    if (fabsf(dy) < WIDTH) {
      const float fx0 = (float)x0;
      // chunk x-range [x0, x0+3] must overlap (px-WIDTH, px+WIDTH)
      if (fx0 + 3.0f > px - WIDTH && fx0 < px + WIDTH) {
        const float dy2 = dy * dy;
#pragma unroll
        for (int j = 0; j < 4; ++j) {
          const float dx = fx0 + (float)j - px;
          const float dist = sqrtf(dy2 + dx * dx);
          if (dist < WIDTH) {
            vv[j] = 1.0f - (dist * INV_MAXD + EPS);
          }
        }
      }
    }

    float4 v;
    v.x = vv[0]; v.y = vv[1]; v.z = vv[2]; v.w = vv[3];
    reinterpret_cast<float4*>(out)[i] = v;
  }
}

extern "C" void kernel_launch(void* const* d_in, const int* in_sizes, int n_in,
                              void* d_out, int out_size, void* d_ws, size_t ws_size,
                              hipStream_t stream) {
  const float* key_points = (const float*)d_in[0];
  float* out = (float*)d_out;

  // 2048 blocks x 256 threads, grid-stride (8 float4 stores per thread)
  dim3 grid(2048);
  dim3 block(256);
  hipLaunchKernelGGL(point_graphic2d_kernel, grid, block, 0, stream,
                     key_points, out);
}

// Round 3
// 15.605 us; speedup vs baseline: 1.0584x; 1.0584x over previous
//
#include <hip/hip_runtime.h>

// PointGraphic2d: 4096x4096 f32 canvas, zero everywhere except a ~40px disk
// around p = key_points[0]*4096. Pure write-BW problem (64 MiB stores).
//
// One row per block (4096 blocks x 256 threads). The disk test
// `|y - py| < 20` is block-uniform -> scalar branch; 4055/4096 blocks issue
// 4 nontemporal 16B zero-stores per thread with no per-store ALU. Disk rows
// (~41) take the compute path.

typedef float floatx4 __attribute__((ext_vector_type(4)));  // native vec for nontemporal builtin

__global__ __launch_bounds__(256) void point_graphic2d_kernel(
    const float* __restrict__ key_points, float* __restrict__ out) {
  constexpr int H = 4096;
  constexpr int W = 4096;
  constexpr int W4 = W / 4;  // 1024 float4 per row
  constexpr float WIDTH = 20.0f;
  constexpr float EPS = 0.001f;
  constexpr float INV_MAXD = 1.0f / 5792.61880957152f;  // 1/(4096*sqrt(2))

  const int y = blockIdx.x;
  const int t = threadIdx.x;

  const float py = key_points[0] * (float)H;
  const float dy = (float)y - py;

  floatx4* __restrict__ row = reinterpret_cast<floatx4*>(out) + (size_t)y * W4;

  if (fabsf(dy) >= WIDTH) {
    // Fast path: block-uniform, pure streaming zero-fill of this row.
    const floatx4 z = {0.0f, 0.0f, 0.0f, 0.0f};
#pragma unroll
    for (int k = 0; k < 4; ++k) {
      __builtin_nontemporal_store(z, row + t + k * 256);
    }
  } else {
    // Disk row: compute per pixel (runs for ~41 of 4096 blocks).
    const float px = key_points[1] * (float)W;
    const float dy2 = dy * dy;
#pragma unroll
    for (int k = 0; k < 4; ++k) {
      const int c = t + k * 256;       // float4 chunk index in row
      const float fx0 = (float)(c << 2);
      floatx4 v = {0.0f, 0.0f, 0.0f, 0.0f};
      // chunk x-range [fx0, fx0+3] overlap with (px-WIDTH, px+WIDTH)?
      if (fx0 + 3.0f > px - WIDTH && fx0 < px + WIDTH) {
#pragma unroll
        for (int j = 0; j < 4; ++j) {
          const float dx = fx0 + (float)j - px;
          const float dist = sqrtf(dy2 + dx * dx);
          if (dist < WIDTH) {
            v[j] = 1.0f - (dist * INV_MAXD + EPS);
          }
        }
      }
      row[c] = v;
    }
  }
}

extern "C" void kernel_launch(void* const* d_in, const int* in_sizes, int n_in,
                              void* d_out, int out_size, void* d_ws, size_t ws_size,
                              hipStream_t stream) {
  const float* key_points = (const float*)d_in[0];
  float* out = (float*)d_out;

  dim3 grid(4096);   // one 4096-px row per block
  dim3 block(256);   // 4x 16B stores per thread
  hipLaunchKernelGGL(point_graphic2d_kernel, grid, block, 0, stream,
                     key_points, out);
}

// Round 4
// 15.198 us; speedup vs baseline: 1.0866x; 1.0267x over previous
//
#include <hip/hip_runtime.h>

// PointGraphic2d: 4096x4096 f32 canvas, zero everywhere except a ~40px disk
// around p = key_points[0]*4096. Pure write problem (64 MiB stores).
//
// One row per block (4096 blocks x 256 threads). The disk test
// `|y - py| < 20` is block-uniform -> scalar branch; 4055/4096 blocks issue
// 4x 16B zero-stores per thread with no per-store ALU.
//
// Round 4: PLAIN stores (no nontemporal hint). The 64 MiB output fits in the
// 256 MiB Infinity Cache; nt forced every store to HBM. Plain stores let the
// MALL absorb the rewrites across graph replays at L3 bandwidth.

typedef float floatx4 __attribute__((ext_vector_type(4)));

__global__ __launch_bounds__(256) void point_graphic2d_kernel(
    const float* __restrict__ key_points, float* __restrict__ out) {
  constexpr int H = 4096;
  constexpr int W = 4096;
  constexpr int W4 = W / 4;  // 1024 float4 per row
  constexpr float WIDTH = 20.0f;
  constexpr float EPS = 0.001f;
  constexpr float INV_MAXD = 1.0f / 5792.61880957152f;  // 1/(4096*sqrt(2))

  const int y = blockIdx.x;
  const int t = threadIdx.x;

  const float py = key_points[0] * (float)H;
  const float dy = (float)y - py;

  floatx4* __restrict__ row = reinterpret_cast<floatx4*>(out) + (size_t)y * W4;

  if (fabsf(dy) >= WIDTH) {
    // Fast path: block-uniform, pure streaming zero-fill of this row.
    const floatx4 z = {0.0f, 0.0f, 0.0f, 0.0f};
#pragma unroll
    for (int k = 0; k < 4; ++k) {
      row[t + k * 256] = z;
    }
  } else {
    // Disk row: compute per pixel (runs for ~41 of 4096 blocks).
    const float px = key_points[1] * (float)W;
    const float dy2 = dy * dy;
#pragma unroll
    for (int k = 0; k < 4; ++k) {
      const int c = t + k * 256;       // float4 chunk index in row
      const float fx0 = (float)(c << 2);
      floatx4 v = {0.0f, 0.0f, 0.0f, 0.0f};
      if (fx0 + 3.0f > px - WIDTH && fx0 < px + WIDTH) {
#pragma unroll
        for (int j = 0; j < 4; ++j) {
          const float dx = fx0 + (float)j - px;
          const float dist = sqrtf(dy2 + dx * dx);
          if (dist < WIDTH) {
            v[j] = 1.0f - (dist * INV_MAXD + EPS);
          }
        }
      }
      row[c] = v;
    }
  }
}

extern "C" void kernel_launch(void* const* d_in, const int* in_sizes, int n_in,
                              void* d_out, int out_size, void* d_ws, size_t ws_size,
                              hipStream_t stream) {
  const float* key_points = (const float*)d_in[0];
  float* out = (float*)d_out;

  dim3 grid(4096);   // one 4096-px row per block
  dim3 block(256);   // 4x 16B stores per thread
  hipLaunchKernelGGL(point_graphic2d_kernel, grid, block, 0, stream,
                     key_points, out);
}